// Round 1
// 885.936 us; speedup vs baseline: 1.1400x; 1.1400x over previous
//
#include <hip/hip_runtime.h>

typedef _Float16 half8 __attribute__((ext_vector_type(8)));
typedef float floatx4 __attribute__((ext_vector_type(4)));

#define B_EDGES 131072
#define NUSERS  500000
#define NCAS    100000

static __device__ __forceinline__ unsigned short f2h(float f) {
  _Float16 h = (_Float16)f;
  return __builtin_bit_cast(unsigned short, h);
}

static __device__ __forceinline__ half8 pack8(float4 a, float4 b) {
  half8 h;
  h[0] = (_Float16)a.x; h[1] = (_Float16)a.y; h[2] = (_Float16)a.z; h[3] = (_Float16)a.w;
  h[4] = (_Float16)b.x; h[5] = (_Float16)b.y; h[6] = (_Float16)b.z; h[7] = (_Float16)b.w;
  return h;
}

// ---------------- init last_idx = -1, counts = 0; pack W into f16 B-fragments ----------------
// packed[((nt*8+ks)*64+lane)*8 + j] = f16(W[(ks*32 + (lane>>4)*8 + j)*128 + nt*16 + (lane&15)])
__global__ __launch_bounds__(256) void k_init(int* lsrc, int* ldst, int* lcas, int* counts,
                                              const float* __restrict__ Ws, const float* __restrict__ Wd,
                                              const float* __restrict__ Wc, unsigned short* __restrict__ packed) {
  int i = blockIdx.x * 256 + threadIdx.x;
  if (i < NUSERS) { lsrc[i] = -1; ldst[i] = -1; }
  if (i < NCAS)   lcas[i] = -1;
  if (i < 96)     counts[i] = 0;   // counters padded: counts[0], counts[32], counts[64]
  if (i < 98304) {
    int w = i >> 15, q = i & 32767;
    int j = q & 7, lane = (q >> 3) & 63, ks = (q >> 9) & 7, nt = q >> 12;
    int k = ks * 32 + ((lane >> 4) << 3) + j;
    int n = nt * 16 + (lane & 15);
    const float* W = (w == 0) ? Ws : ((w == 1) ? Wd : Wc);
    packed[i] = f2h(W[k * 128 + n]);
  }
}

// ---------------- scatter: last_idx[id] = max batch pos ----------------
__global__ __launch_bounds__(256) void k_scatter(const int* __restrict__ s, const int* __restrict__ d,
                                                 const int* __restrict__ c,
                                                 int* lsrc, int* ldst, int* lcas) {
  int i = blockIdx.x * 256 + threadIdx.x;  // grid exact: 512*256 = 131072
  atomicMax(&lsrc[s[i]], i);
  atomicMax(&ldst[d[i]], i);
  atomicMax(&lcas[c[i]], i);
}

// ---------------- compact active edges per type (block-aggregated atomics) ----------------
// spans of 4096 elems, region-aligned: src blocks [0,123), dst [123,246), cas [246,271).
// ONE global atomicAdd per block, onto counters padded 128 B apart (no same-line storm).
__global__ __launch_bounds__(256) void k_compact(const int* __restrict__ lsrc, const int* __restrict__ ldst,
                                                 const int* __restrict__ lcas,
                                                 int* counts, int* list_src, int* list_dst, int* list_cas) {
  __shared__ int s_count;
  __shared__ int s_cursor;
  int b = blockIdx.x;
  const int* last; int* list; int* cnt; int base; int n;
  if (b < 123)      { last = lsrc; list = list_src; cnt = counts + 0;  base = b * 4096;         n = NUSERS; }
  else if (b < 246) { last = ldst; list = list_dst; cnt = counts + 32; base = (b - 123) * 4096; n = NUSERS; }
  else              { last = lcas; list = list_cas; cnt = counts + 64; base = (b - 246) * 4096; n = NCAS;  }
  int tid = threadIdx.x, lane = tid & 63;
  if (tid == 0) s_count = 0;
  __syncthreads();
  int e[16]; int myc = 0;
#pragma unroll
  for (int it = 0; it < 16; ++it) {
    int i = base + it * 256 + tid;
    e[it] = (i < n) ? last[i] : -1;
    myc += (e[it] >= 0) ? 1 : 0;
  }
#pragma unroll
  for (int off = 32; off > 0; off >>= 1) myc += __shfl_down(myc, off);
  if (lane == 0) atomicAdd(&s_count, myc);
  __syncthreads();
  if (tid == 0) s_cursor = atomicAdd(cnt, s_count);
  __syncthreads();
#pragma unroll
  for (int it = 0; it < 16; ++it) {
    bool act = (e[it] >= 0);
    unsigned long long m = __ballot(act);
    if (m) {
      int before = __popcll(m & ((1ull << lane) - 1ull));
      int leader = __ffsll((unsigned long long)m) - 1;
      int wbase = 0;
      if (lane == leader) wbase = atomicAdd(&s_cursor, __popcll(m));
      wbase = __shfl(wbase, leader);
      if (act) list[wbase + before] = e[it];
    }
  }
}

// ---------------- fused: message GEMM (blocks 0..2559) + fill (blocks 2560..140059) ----------------
// GEMM blocks dispatched first so the latency-bound gather phase starts immediately;
// fill's streaming zero-writes backfill and overlap with it.
__global__ __launch_bounds__(256, 3) void k_msgs_fill(
    const int* __restrict__ sid, const int* __restrict__ did, const int* __restrict__ cid,
    const float* __restrict__ et, const float* __restrict__ pub,
    const float* __restrict__ us, const float* __restrict__ ud, const float* __restrict__ cs,
    const float* __restrict__ ulu,
    const float* __restrict__ wtu, const float* __restrict__ btu,
    const float* __restrict__ wtc, const float* __restrict__ btc,
    const float* __restrict__ bsrc, const float* __restrict__ bdst, const float* __restrict__ bcas,
    const int* __restrict__ counts,
    const int* __restrict__ list_src, const int* __restrict__ list_dst, const int* __restrict__ list_cas,
    const unsigned short* __restrict__ packedW,
    const int* __restrict__ lsrc, const int* __restrict__ ldst, const int* __restrict__ lcas,
    float* __restrict__ out) {
  __shared__ alignas(16) unsigned short A[32][264];
  __shared__ int node_out[32];

  int b = blockIdx.x;
  int tid  = threadIdx.x;

  if (b >= 2560) {
    // -------- fill path: 8 rows per block, 32 lanes per row --------
    int row  = (b - 2560) * 8 + (tid >> 5);  // 137500*8 = 1,100,000 rows
    int lane31 = tid & 31;
    const int* last; float* msg; float* to; float* ko; int local;
    if (row < 500000)       { local = row;           last = lsrc; msg = out;             to = out + 64000000;  ko = out + 64500000;  }
    else if (row < 1000000) { local = row - 500000;  last = ldst; msg = out + 65000000;  to = out + 129000000; ko = out + 129500000; }
    else                    { local = row - 1000000; last = lcas; msg = out + 130000000; to = out + 142800000; ko = out + 142900000; }
    int e = last[local];
    if (e < 0) {
      float4 z = make_float4(0.f, 0.f, 0.f, 0.f);
      ((float4*)(msg + (size_t)local * 128))[lane31] = z;
      if (lane31 == 0) { to[local] = 0.f; ko[local] = 0.f; }
    } else if (lane31 == 0) {
      to[local] = et[e]; ko[local] = 1.f;
    }
    return;
  }

  // -------- GEMM path --------
  int type, tile, stride;
  const int* list; const int* oid; const float* wt; const float* bt; const float* bias;
  const unsigned short* pW; float* om; int count;
  if (b < 1024)      { type = 0; tile = b;        stride = 1024; list = list_src; count = counts[0];  oid = sid; wt = wtu; bt = btu; bias = bsrc; pW = packedW;         om = out; }
  else if (b < 2048) { type = 1; tile = b - 1024; stride = 1024; list = list_dst; count = counts[32]; oid = did; wt = wtu; bt = btu; bias = bdst; pW = packedW + 32768; om = out + 65000000; }
  else               { type = 2; tile = b - 2048; stride = 512;  list = list_cas; count = counts[64]; oid = cid; wt = wtc; bt = btc; bias = bcas; pW = packedW + 65536; om = out + 130000000; }

  int lane = tid & 63;
  int wv   = tid >> 6;
  int m_lo = lane & 15;
  int kgrp = lane >> 4;

  // persistent W fragments: wave wv -> N-tiles {2wv, 2wv+1}, 8 K-steps each
  half8 wf[2][8];
  const half8* pw8 = (const half8*)pW;
#pragma unroll
  for (int ntl = 0; ntl < 2; ++ntl)
#pragma unroll
    for (int ks = 0; ks < 8; ++ks)
      wf[ntl][ks] = pw8[((wv * 2 + ntl) * 8 + ks) * 64 + lane];
  float bias0 = bias[wv * 32 + m_lo];
  float bias1 = bias[wv * 32 + 16 + m_lo];

  int r = tid >> 3, t8 = tid & 7;  // 8 staging threads per row
  // hoisted per-thread time-encoder coefficients (cols t8*8 .. t8*8+7)
  float4 w4a = ((const float4*)wt)[t8 * 2];
  float4 w4b = ((const float4*)wt)[t8 * 2 + 1];
  float4 b4a = ((const float4*)bt)[t8 * 2];
  float4 b4b = ((const float4*)bt)[t8 * 2 + 1];

  int tiles = (count + 31) >> 5;

  for (int t = tile; t < tiles; t += stride) {
    __syncthreads();  // protect LDS from previous iteration's readers
    int idx = t * 32 + r;
    int e = (idx < count) ? list[idx] : -1;
    if (e >= 0) {
      int s = sid[e], d = did[e], c = cid[e];
      if (t8 == 0) node_out[r] = oid[e];
      const float* base0 = us + (size_t)s * 64;
      const float* base1 = ud + (size_t)d * 64;
      const float* base2 = cs + (size_t)c * 64;
#pragma unroll
      for (int a = 0; a < 3; ++a) {
        const float* bp = (a == 0) ? base0 : ((a == 1) ? base1 : base2);
        float4 v0 = ((const float4*)bp)[t8 * 2];
        float4 v1 = ((const float4*)bp)[t8 * 2 + 1];
        *(half8*)&A[r][a * 64 + t8 * 8] = pack8(v0, v1);
      }
      float ete = et[e];
      float dt;
      if (type == 0)      dt = ete - ulu[s];
      else if (type == 1) dt = ete - ulu[d];
      else                dt = ete - pub[e];
      float4 c0, c1;
      c0.x = __cosf(dt * w4a.x + b4a.x);
      c0.y = __cosf(dt * w4a.y + b4a.y);
      c0.z = __cosf(dt * w4a.z + b4a.z);
      c0.w = __cosf(dt * w4a.w + b4a.w);
      c1.x = __cosf(dt * w4b.x + b4b.x);
      c1.y = __cosf(dt * w4b.y + b4b.y);
      c1.z = __cosf(dt * w4b.z + b4b.z);
      c1.w = __cosf(dt * w4b.w + b4b.w);
      *(half8*)&A[r][192 + t8 * 8] = pack8(c0, c1);
    } else {
      half8 z = {0, 0, 0, 0, 0, 0, 0, 0};
#pragma unroll
      for (int a = 0; a < 3; ++a) *(half8*)&A[r][a * 64 + t8 * 8] = z;
      *(half8*)&A[r][192 + t8 * 8] = z;
      if (t8 == 0) node_out[r] = -1;
    }
    __syncthreads();

    floatx4 acc00 = {0.f, 0.f, 0.f, 0.f}, acc01 = {0.f, 0.f, 0.f, 0.f};
    floatx4 acc10 = {0.f, 0.f, 0.f, 0.f}, acc11 = {0.f, 0.f, 0.f, 0.f};
#pragma unroll
    for (int ks = 0; ks < 8; ++ks) {
      half8 a0 = *(const half8*)&A[m_lo][ks * 32 + kgrp * 8];       // A[m=lane&15][k=kgrp*8+j]
      half8 a1 = *(const half8*)&A[16 + m_lo][ks * 32 + kgrp * 8];
      acc00 = __builtin_amdgcn_mfma_f32_16x16x32_f16(a0, wf[0][ks], acc00, 0, 0, 0);
      acc01 = __builtin_amdgcn_mfma_f32_16x16x32_f16(a0, wf[1][ks], acc01, 0, 0, 0);
      acc10 = __builtin_amdgcn_mfma_f32_16x16x32_f16(a1, wf[0][ks], acc10, 0, 0, 0);
      acc11 = __builtin_amdgcn_mfma_f32_16x16x32_f16(a1, wf[1][ks], acc11, 0, 0, 0);
    }

    // epilogue: D layout col = lane&15, row = kgrp*4 + reg
#pragma unroll
    for (int rg = 0; rg < 4; ++rg) {
      int m0 = kgrp * 4 + rg;
      int n0 = node_out[m0];
      if (n0 >= 0) {
        float* orow = om + (size_t)n0 * 128 + wv * 32 + m_lo;
        orow[0]  = acc00[rg] + bias0;
        orow[16] = acc01[rg] + bias1;
      }
      int n1 = node_out[16 + m0];
      if (n1 >= 0) {
        float* orow = om + (size_t)n1 * 128 + wv * 32 + m_lo;
        orow[0]  = acc10[rg] + bias0;
        orow[16] = acc11[rg] + bias1;
      }
    }
  }
}

extern "C" void kernel_launch(void* const* d_in, const int* in_sizes, int n_in,
                              void* d_out, int out_size, void* d_ws, size_t ws_size,
                              hipStream_t stream) {
  (void)in_sizes; (void)n_in; (void)out_size; (void)ws_size;
  const int*   sid = (const int*)d_in[0];
  const int*   did = (const int*)d_in[1];
  const int*   cid = (const int*)d_in[2];
  const float* et  = (const float*)d_in[3];
  const float* pub = (const float*)d_in[4];
  const float* us  = (const float*)d_in[5];
  const float* ud  = (const float*)d_in[6];
  const float* cs  = (const float*)d_in[7];
  const float* ulu = (const float*)d_in[8];
  const float* wtu = (const float*)d_in[9];
  const float* btu = (const float*)d_in[10];
  const float* wtc = (const float*)d_in[11];
  const float* btc = (const float*)d_in[12];
  const float* Ws  = (const float*)d_in[13];
  const float* bs  = (const float*)d_in[14];
  const float* Wd  = (const float*)d_in[15];
  const float* bd  = (const float*)d_in[16];
  const float* Wc  = (const float*)d_in[17];
  const float* bc  = (const float*)d_in[18];
  float* out = (float*)d_out;

  int* wsI       = (int*)d_ws;
  int* lsrc      = wsI;
  int* ldst      = wsI + 500000;
  int* lcas      = wsI + 1000000;
  int* counts    = wsI + 1100000;   // 96 ints (3 counters padded 128 B apart)
  int* list_src  = wsI + 1100096;   // 131072
  int* list_dst  = wsI + 1231168;   // 131072
  int* list_cas  = wsI + 1362240;   // 100000
  unsigned short* packedW = (unsigned short*)(wsI + 1462240);  // 3*32768 u16, 16B-aligned

  k_init<<<1954, 256, 0, stream>>>(lsrc, ldst, lcas, counts, Ws, Wd, Wc, packedW);
  k_scatter<<<512, 256, 0, stream>>>(sid, did, cid, lsrc, ldst, lcas);
  k_compact<<<271, 256, 0, stream>>>(lsrc, ldst, lcas, counts, list_src, list_dst, list_cas);
  k_msgs_fill<<<140060, 256, 0, stream>>>(sid, did, cid, et, pub, us, ud, cs, ulu,
                                          wtu, btu, wtc, btc, bs, bd, bc,
                                          counts, list_src, list_dst, list_cas, packedW,
                                          lsrc, ldst, lcas, out);
}

// Round 2
// 870.964 us; speedup vs baseline: 1.1596x; 1.0172x over previous
//
#include <hip/hip_runtime.h>

typedef _Float16 half8 __attribute__((ext_vector_type(8)));
typedef float floatx4 __attribute__((ext_vector_type(4)));

#define B_EDGES 131072
#define NUSERS  500000
#define NCAS    100000

static __device__ __forceinline__ unsigned short f2h(float f) {
  _Float16 h = (_Float16)f;
  return __builtin_bit_cast(unsigned short, h);
}

static __device__ __forceinline__ half8 pack8(float4 a, float4 b) {
  half8 h;
  h[0] = (_Float16)a.x; h[1] = (_Float16)a.y; h[2] = (_Float16)a.z; h[3] = (_Float16)a.w;
  h[4] = (_Float16)b.x; h[5] = (_Float16)b.y; h[6] = (_Float16)b.z; h[7] = (_Float16)b.w;
  return h;
}

// ---------------- init last_idx = -1, counts = 0; pack W into f16 B-fragments ----------------
// packed[((nt*8+ks)*64+lane)*8 + j] = f16(W[(ks*32 + (lane>>4)*8 + j)*128 + nt*16 + (lane&15)])
__global__ __launch_bounds__(256) void k_init(int* lsrc, int* ldst, int* lcas, int* counts,
                                              const float* __restrict__ Ws, const float* __restrict__ Wd,
                                              const float* __restrict__ Wc, unsigned short* __restrict__ packed) {
  int i = blockIdx.x * 256 + threadIdx.x;
  if (i < NUSERS) { lsrc[i] = -1; ldst[i] = -1; }
  if (i < NCAS)   lcas[i] = -1;
  if (i < 96)     counts[i] = 0;   // counters padded: counts[0], counts[32], counts[64]
  if (i < 98304) {
    int w = i >> 15, q = i & 32767;
    int j = q & 7, lane = (q >> 3) & 63, ks = (q >> 9) & 7, nt = q >> 12;
    int k = ks * 32 + ((lane >> 4) << 3) + j;
    int n = nt * 16 + (lane & 15);
    const float* W = (w == 0) ? Ws : ((w == 1) ? Wd : Wc);
    packed[i] = f2h(W[k * 128 + n]);
  }
}

// ---------------- scatter: last_idx[id] = max batch pos ----------------
__global__ __launch_bounds__(256) void k_scatter(const int* __restrict__ s, const int* __restrict__ d,
                                                 const int* __restrict__ c,
                                                 int* lsrc, int* ldst, int* lcas) {
  int i = blockIdx.x * 256 + threadIdx.x;  // grid exact: 512*256 = 131072
  atomicMax(&lsrc[s[i]], i);
  atomicMax(&ldst[d[i]], i);
  atomicMax(&lcas[c[i]], i);
}

// ---------------- compact active edges per type (block-aggregated atomics) ----------------
// spans of 4096 elems, region-aligned: src blocks [0,123), dst [123,246), cas [246,271).
// ONE global atomicAdd per block, onto counters padded 128 B apart (no same-line storm).
__global__ __launch_bounds__(256) void k_compact(const int* __restrict__ lsrc, const int* __restrict__ ldst,
                                                 const int* __restrict__ lcas,
                                                 int* counts, int* list_src, int* list_dst, int* list_cas) {
  __shared__ int s_count;
  __shared__ int s_cursor;
  int b = blockIdx.x;
  const int* last; int* list; int* cnt; int base; int n;
  if (b < 123)      { last = lsrc; list = list_src; cnt = counts + 0;  base = b * 4096;         n = NUSERS; }
  else if (b < 246) { last = ldst; list = list_dst; cnt = counts + 32; base = (b - 123) * 4096; n = NUSERS; }
  else              { last = lcas; list = list_cas; cnt = counts + 64; base = (b - 246) * 4096; n = NCAS;  }
  int tid = threadIdx.x, lane = tid & 63;
  if (tid == 0) s_count = 0;
  __syncthreads();
  int e[16]; int myc = 0;
#pragma unroll
  for (int it = 0; it < 16; ++it) {
    int i = base + it * 256 + tid;
    e[it] = (i < n) ? last[i] : -1;
    myc += (e[it] >= 0) ? 1 : 0;
  }
#pragma unroll
  for (int off = 32; off > 0; off >>= 1) myc += __shfl_down(myc, off);
  if (lane == 0) atomicAdd(&s_count, myc);
  __syncthreads();
  if (tid == 0) s_cursor = atomicAdd(cnt, s_count);
  __syncthreads();
#pragma unroll
  for (int it = 0; it < 16; ++it) {
    bool act = (e[it] >= 0);
    unsigned long long m = __ballot(act);
    if (m) {
      int before = __popcll(m & ((1ull << lane) - 1ull));
      int leader = __ffsll((unsigned long long)m) - 1;
      int wbase = 0;
      if (lane == leader) wbase = atomicAdd(&s_cursor, __popcll(m));
      wbase = __shfl(wbase, leader);
      if (act) list[wbase + before] = e[it];
    }
  }
}

// ---------------- fused: message GEMM (blocks 0..2559) + grid-stride fill (blocks 2560..4607) ----
// GEMM blocks dispatched first (latency-bound gather phase starts immediately); fill blocks are
// PERSISTENT grid-stride loops (68 iterations of 8 rows each) so stores issue back-to-back and the
// end-of-kernel vmcnt drain is paid once per block, not once per 4 KB.
#define FILLB 2048
__global__ __launch_bounds__(256, 3) void k_msgs_fill(
    const int* __restrict__ sid, const int* __restrict__ did, const int* __restrict__ cid,
    const float* __restrict__ et, const float* __restrict__ pub,
    const float* __restrict__ us, const float* __restrict__ ud, const float* __restrict__ cs,
    const float* __restrict__ ulu,
    const float* __restrict__ wtu, const float* __restrict__ btu,
    const float* __restrict__ wtc, const float* __restrict__ btc,
    const float* __restrict__ bsrc, const float* __restrict__ bdst, const float* __restrict__ bcas,
    const int* __restrict__ counts,
    const int* __restrict__ list_src, const int* __restrict__ list_dst, const int* __restrict__ list_cas,
    const unsigned short* __restrict__ packedW,
    const int* __restrict__ lsrc, const int* __restrict__ ldst, const int* __restrict__ lcas,
    float* __restrict__ out) {
  __shared__ alignas(16) unsigned short A[32][264];
  __shared__ int node_out[32];

  int b = blockIdx.x;
  int tid  = threadIdx.x;

  if (b >= 2560) {
    // -------- fill path: grid-stride over 137,500 groups of 8 rows; 32 lanes per row --------
    int lane31 = tid & 31;
    int rsub   = tid >> 5;  // 0..7
    for (int g = b - 2560; g < 137500; g += FILLB) {
      int row = g * 8 + rsub;  // region boundaries (500000, 1000000) are multiples of 8
      const int* last; float* msg; float* to; float* ko; int local;
      if (row < 500000)       { local = row;           last = lsrc; msg = out;             to = out + 64000000;  ko = out + 64500000;  }
      else if (row < 1000000) { local = row - 500000;  last = ldst; msg = out + 65000000;  to = out + 129000000; ko = out + 129500000; }
      else                    { local = row - 1000000; last = lcas; msg = out + 130000000; to = out + 142800000; ko = out + 142900000; }
      int e = last[local];
      if (e < 0) {
        float4 z = make_float4(0.f, 0.f, 0.f, 0.f);
        ((float4*)(msg + (size_t)local * 128))[lane31] = z;
        if (lane31 == 0) { to[local] = 0.f; ko[local] = 0.f; }
      } else if (lane31 == 0) {
        to[local] = et[e]; ko[local] = 1.f;
      }
    }
    return;
  }

  // -------- GEMM path --------
  int type, tile, stride;
  const int* list; const int* oid; const float* wt; const float* bt; const float* bias;
  const unsigned short* pW; float* om; int count;
  if (b < 1024)      { type = 0; tile = b;        stride = 1024; list = list_src; count = counts[0];  oid = sid; wt = wtu; bt = btu; bias = bsrc; pW = packedW;         om = out; }
  else if (b < 2048) { type = 1; tile = b - 1024; stride = 1024; list = list_dst; count = counts[32]; oid = did; wt = wtu; bt = btu; bias = bdst; pW = packedW + 32768; om = out + 65000000; }
  else               { type = 2; tile = b - 2048; stride = 512;  list = list_cas; count = counts[64]; oid = cid; wt = wtc; bt = btc; bias = bcas; pW = packedW + 65536; om = out + 130000000; }

  int lane = tid & 63;
  int wv   = tid >> 6;
  int m_lo = lane & 15;
  int kgrp = lane >> 4;

  // persistent W fragments: wave wv -> N-tiles {2wv, 2wv+1}, 8 K-steps each
  half8 wf[2][8];
  const half8* pw8 = (const half8*)pW;
#pragma unroll
  for (int ntl = 0; ntl < 2; ++ntl)
#pragma unroll
    for (int ks = 0; ks < 8; ++ks)
      wf[ntl][ks] = pw8[((wv * 2 + ntl) * 8 + ks) * 64 + lane];
  float bias0 = bias[wv * 32 + m_lo];
  float bias1 = bias[wv * 32 + 16 + m_lo];

  int r = tid >> 3, t8 = tid & 7;  // 8 staging threads per row
  // hoisted per-thread time-encoder coefficients (cols t8*8 .. t8*8+7)
  float4 w4a = ((const float4*)wt)[t8 * 2];
  float4 w4b = ((const float4*)wt)[t8 * 2 + 1];
  float4 b4a = ((const float4*)bt)[t8 * 2];
  float4 b4b = ((const float4*)bt)[t8 * 2 + 1];

  int tiles = (count + 31) >> 5;

  for (int t = tile; t < tiles; t += stride) {
    __syncthreads();  // protect LDS from previous iteration's readers
    int idx = t * 32 + r;
    int e = (idx < count) ? list[idx] : -1;
    if (e >= 0) {
      int s = sid[e], d = did[e], c = cid[e];
      if (t8 == 0) node_out[r] = oid[e];
      const float* base0 = us + (size_t)s * 64;
      const float* base1 = ud + (size_t)d * 64;
      const float* base2 = cs + (size_t)c * 64;
#pragma unroll
      for (int a = 0; a < 3; ++a) {
        const float* bp = (a == 0) ? base0 : ((a == 1) ? base1 : base2);
        float4 v0 = ((const float4*)bp)[t8 * 2];
        float4 v1 = ((const float4*)bp)[t8 * 2 + 1];
        *(half8*)&A[r][a * 64 + t8 * 8] = pack8(v0, v1);
      }
      float ete = et[e];
      float dt;
      if (type == 0)      dt = ete - ulu[s];
      else if (type == 1) dt = ete - ulu[d];
      else                dt = ete - pub[e];
      float4 c0, c1;
      c0.x = __cosf(dt * w4a.x + b4a.x);
      c0.y = __cosf(dt * w4a.y + b4a.y);
      c0.z = __cosf(dt * w4a.z + b4a.z);
      c0.w = __cosf(dt * w4a.w + b4a.w);
      c1.x = __cosf(dt * w4b.x + b4b.x);
      c1.y = __cosf(dt * w4b.y + b4b.y);
      c1.z = __cosf(dt * w4b.z + b4b.z);
      c1.w = __cosf(dt * w4b.w + b4b.w);
      *(half8*)&A[r][192 + t8 * 8] = pack8(c0, c1);
    } else {
      half8 z = {0, 0, 0, 0, 0, 0, 0, 0};
#pragma unroll
      for (int a = 0; a < 3; ++a) *(half8*)&A[r][a * 64 + t8 * 8] = z;
      *(half8*)&A[r][192 + t8 * 8] = z;
      if (t8 == 0) node_out[r] = -1;
    }
    __syncthreads();

    floatx4 acc00 = {0.f, 0.f, 0.f, 0.f}, acc01 = {0.f, 0.f, 0.f, 0.f};
    floatx4 acc10 = {0.f, 0.f, 0.f, 0.f}, acc11 = {0.f, 0.f, 0.f, 0.f};
#pragma unroll
    for (int ks = 0; ks < 8; ++ks) {
      half8 a0 = *(const half8*)&A[m_lo][ks * 32 + kgrp * 8];       // A[m=lane&15][k=kgrp*8+j]
      half8 a1 = *(const half8*)&A[16 + m_lo][ks * 32 + kgrp * 8];
      acc00 = __builtin_amdgcn_mfma_f32_16x16x32_f16(a0, wf[0][ks], acc00, 0, 0, 0);
      acc01 = __builtin_amdgcn_mfma_f32_16x16x32_f16(a0, wf[1][ks], acc01, 0, 0, 0);
      acc10 = __builtin_amdgcn_mfma_f32_16x16x32_f16(a1, wf[0][ks], acc10, 0, 0, 0);
      acc11 = __builtin_amdgcn_mfma_f32_16x16x32_f16(a1, wf[1][ks], acc11, 0, 0, 0);
    }

    // epilogue: D layout col = lane&15, row = kgrp*4 + reg
#pragma unroll
    for (int rg = 0; rg < 4; ++rg) {
      int m0 = kgrp * 4 + rg;
      int n0 = node_out[m0];
      if (n0 >= 0) {
        float* orow = om + (size_t)n0 * 128 + wv * 32 + m_lo;
        orow[0]  = acc00[rg] + bias0;
        orow[16] = acc01[rg] + bias1;
      }
      int n1 = node_out[16 + m0];
      if (n1 >= 0) {
        float* orow = om + (size_t)n1 * 128 + wv * 32 + m_lo;
        orow[0]  = acc10[rg] + bias0;
        orow[16] = acc11[rg] + bias1;
      }
    }
  }
}

extern "C" void kernel_launch(void* const* d_in, const int* in_sizes, int n_in,
                              void* d_out, int out_size, void* d_ws, size_t ws_size,
                              hipStream_t stream) {
  (void)in_sizes; (void)n_in; (void)out_size; (void)ws_size;
  const int*   sid = (const int*)d_in[0];
  const int*   did = (const int*)d_in[1];
  const int*   cid = (const int*)d_in[2];
  const float* et  = (const float*)d_in[3];
  const float* pub = (const float*)d_in[4];
  const float* us  = (const float*)d_in[5];
  const float* ud  = (const float*)d_in[6];
  const float* cs  = (const float*)d_in[7];
  const float* ulu = (const float*)d_in[8];
  const float* wtu = (const float*)d_in[9];
  const float* btu = (const float*)d_in[10];
  const float* wtc = (const float*)d_in[11];
  const float* btc = (const float*)d_in[12];
  const float* Ws  = (const float*)d_in[13];
  const float* bs  = (const float*)d_in[14];
  const float* Wd  = (const float*)d_in[15];
  const float* bd  = (const float*)d_in[16];
  const float* Wc  = (const float*)d_in[17];
  const float* bc  = (const float*)d_in[18];
  float* out = (float*)d_out;

  int* wsI       = (int*)d_ws;
  int* lsrc      = wsI;
  int* ldst      = wsI + 500000;
  int* lcas      = wsI + 1000000;
  int* counts    = wsI + 1100000;   // 96 ints (3 counters padded 128 B apart)
  int* list_src  = wsI + 1100096;   // 131072
  int* list_dst  = wsI + 1231168;   // 131072
  int* list_cas  = wsI + 1362240;   // 100000
  unsigned short* packedW = (unsigned short*)(wsI + 1462240);  // 3*32768 u16, 16B-aligned

  k_init<<<1954, 256, 0, stream>>>(lsrc, ldst, lcas, counts, Ws, Wd, Wc, packedW);
  k_scatter<<<512, 256, 0, stream>>>(sid, did, cid, lsrc, ldst, lcas);
  k_compact<<<271, 256, 0, stream>>>(lsrc, ldst, lcas, counts, list_src, list_dst, list_cas);
  k_msgs_fill<<<2560 + FILLB, 256, 0, stream>>>(sid, did, cid, et, pub, us, ud, cs, ulu,
                                                wtu, btu, wtc, btc, bs, bd, bc,
                                                counts, list_src, list_dst, list_cas, packedW,
                                                lsrc, ldst, lcas, out);
}